// Round 9
// baseline (251.283 us; speedup 1.0000x reference)
//
#include <hip/hip_runtime.h>
#include <math.h>

// CPQuadRankLayer: B=16, N=2048, IN=OUT=256, R=64, Q=4.
// out[b,n,o] = sum_r ( prod_q rmsnorm_r(x[b,n,q,:] @ Fq[n]^T) )[r] * gain[n] * Fo[n,r,o]
//              + mean_q x[b,n,q,o]
//
// R9: "LDS-free streaming". R5-R8 showed the design is serialization-bound
// (no pipe >50%, barriers/DMA on the critical path). Key observation: factor
// rows are consumed by exactly ONE wave (q=wid>>1, r-half=wid&1) and fo is a
// pure broadcast — nothing needs LDS staging. So the projection loop reads
// factors and x directly global->VGPR (lane-dedupe + L1 handle the bh
// duplicate and 64B segmentation; 128B-line halves are reused by phase p+1),
// and the out-GEMM reads fo coalesced (1KB/instr/wave, 8x L1 temporal reuse).
// Main loop: ZERO barriers, zero DMA, zero LDS. LDS only for P/RMS/merge
// (16.5KB, 3 __syncthreads per n). 512 thr, grid 2048, (512,3) -> 24 waves/CU.

#define NN 2048

__global__ __launch_bounds__(512, 3) void cpquad_kernel(
    const float* __restrict__ x,
    const float* __restrict__ ftl, const float* __restrict__ ftr,
    const float* __restrict__ fbl, const float* __restrict__ fbr,
    const float* __restrict__ fout, const float* __restrict__ gain,
    float* __restrict__ out) {

  __shared__ float s_ps[4096]; // [4 q][16 b][64 r]; plane0 overwritten by merged
  __shared__ float s_rr[64];   // [4 q][16 b] 1/rms

  const int t = threadIdx.x, lane = t & 63, wid = t >> 6;
  const int n = blockIdx.x;
  const float gn = gain[n];

  // decomposition: t = qq(2b) | rg(4b) | bh(1b) | iseg(2b)
  const int iseg = t & 3;         // 4-float i-slot within a 16-i slice
  const int bh   = (t >> 2) & 1;  // b half
  const int rg   = (t >> 3) & 15; // rows rg + {0,16,32,48} (bit3 of rg = wid&1)
  const int qq   = t >> 7;        // quadrant ( = wid>>1 )

  const float* fq0 = (qq == 0) ? ftl : ((qq == 1) ? ftr : ((qq == 2) ? fbl : fbr));
  // fv[k] row r=k*16+rg, phase slot p*16+iseg*4
  const float* fbase = fq0 + ((size_t)n * 64 + rg) * 256 + (iseg << 2);
  // xv[b] row (b, qq), b = bh*8 + j
  const float* xbase = x + (((size_t)(bh * 8) * NN + n) * 4 + qq) * 256 + (iseg << 2);

  float acc[4][8];
#pragma unroll
  for (int k = 0; k < 4; ++k)
#pragma unroll
    for (int b = 0; b < 8; ++b) acc[k][b] = 0.0f;

  // ---------- projection: 16 i-slices, direct global->reg, no barriers ------
#pragma unroll 2
  for (int p = 0; p < 16; ++p) {
    float4 fv[4];
#pragma unroll
    for (int k = 0; k < 4; ++k)
      fv[k] = *(const float4*)(fbase + k * 4096 + p * 16);
#pragma unroll
    for (int h2 = 0; h2 < 2; ++h2) {
      float4 xv[4];
#pragma unroll
      for (int bb = 0; bb < 4; ++bb)
        xv[bb] = *(const float4*)(xbase + (size_t)(h2 * 4 + bb) * (NN * 1024) + p * 16);
#pragma unroll
      for (int k = 0; k < 4; ++k)
#pragma unroll
        for (int bb = 0; bb < 4; ++bb) {
          acc[k][h2 * 4 + bb] = fmaf(fv[k].x, xv[bb].x, acc[k][h2 * 4 + bb]);
          acc[k][h2 * 4 + bb] = fmaf(fv[k].y, xv[bb].y, acc[k][h2 * 4 + bb]);
          acc[k][h2 * 4 + bb] = fmaf(fv[k].z, xv[bb].z, acc[k][h2 * 4 + bb]);
          acc[k][h2 * 4 + bb] = fmaf(fv[k].w, xv[bb].w, acc[k][h2 * 4 + bb]);
        }
    }
  }

  // ---------- reduce over iseg, write P ----------
#pragma unroll
  for (int k = 0; k < 4; ++k)
#pragma unroll
    for (int b = 0; b < 8; ++b) {
      float v = acc[k][b];
      v += __shfl_xor(v, 1);
      v += __shfl_xor(v, 2);
      acc[k][b] = v;
    }
#pragma unroll
  for (int k = 0; k < 4; ++k) {
    if (iseg == k) { // static acc index (rule #20)
#pragma unroll
      for (int b = 0; b < 8; ++b)
        s_ps[qq * 1024 + (bh * 8 + b) * 64 + k * 16 + rg] = acc[k][b];
    }
  }
  __syncthreads();

  // ---------- RMS per (q,b) row ----------
#pragma unroll
  for (int j = 0; j < 8; ++j) {
    const int row = wid * 8 + j; // row = q*16 + b
    const float v = s_ps[row * 64 + lane];
    float ssum = v * v;
#pragma unroll
    for (int d = 1; d < 64; d <<= 1) ssum += __shfl_xor(ssum, d);
    if (lane == 0) s_rr[row] = 1.0f / sqrtf(ssum * (1.0f / 64.0f) + 1e-6f);
  }
  __syncthreads();

  // ---------- merged[b][r] -> s_ps plane 0 (element-owned, race-free) -------
#pragma unroll
  for (int e0 = 0; e0 < 2; ++e0) {
    const int e = t + e0 * 512;
    const int b = e >> 6, r = e & 63;
    float m = gn;
#pragma unroll
    for (int q = 0; q < 4; ++q) m *= s_ps[q * 1024 + b * 64 + r] * s_rr[q * 16 + b];
    s_ps[b * 64 + r] = m;
  }
  __syncthreads();

  // ---------- out GEMM: direct coalesced fo reads (broadcast across waves) --
  // thread = (2 b) x (4 o), o = lane*4. m-values via readlane off a per-lane
  // merged row (no LDS in the loop).
  const float mv0 = s_ps[(wid * 2 + 0) * 64 + lane];
  const float mv1 = s_ps[(wid * 2 + 1) * 64 + lane];
  const float* fo_n = fout + (size_t)n * 16384 + (lane << 2);

  float oa[2][4] = {{0.f, 0.f, 0.f, 0.f}, {0.f, 0.f, 0.f, 0.f}};
#pragma unroll 8
  for (int rr = 0; rr < 64; ++rr) {
    const float4 f4 = *(const float4*)(fo_n + rr * 256);
    const float m0 = __uint_as_float(__builtin_amdgcn_readlane(__float_as_uint(mv0), rr));
    const float m1 = __uint_as_float(__builtin_amdgcn_readlane(__float_as_uint(mv1), rr));
    oa[0][0] = fmaf(m0, f4.x, oa[0][0]); oa[0][1] = fmaf(m0, f4.y, oa[0][1]);
    oa[0][2] = fmaf(m0, f4.z, oa[0][2]); oa[0][3] = fmaf(m0, f4.w, oa[0][3]);
    oa[1][0] = fmaf(m1, f4.x, oa[1][0]); oa[1][1] = fmaf(m1, f4.y, oa[1][1]);
    oa[1][2] = fmaf(m1, f4.z, oa[1][2]); oa[1][3] = fmaf(m1, f4.w, oa[1][3]);
  }

  // ---------- residual: tail re-read of x (coalesced, L2/L3-warm) + store ---
#pragma unroll
  for (int bb = 0; bb < 2; ++bb) {
    const int b = wid * 2 + bb;
    const float* xe = x + (((size_t)b * NN + n) * 4) * 256 + (lane << 2);
    float4 x0 = *(const float4*)(xe);
    float4 x1 = *(const float4*)(xe + 256);
    float4 x2 = *(const float4*)(xe + 512);
    float4 x3 = *(const float4*)(xe + 768);
    float4 o4;
    o4.x = oa[bb][0] + 0.25f * (x0.x + x1.x + x2.x + x3.x);
    o4.y = oa[bb][1] + 0.25f * (x0.y + x1.y + x2.y + x3.y);
    o4.z = oa[bb][2] + 0.25f * (x0.z + x1.z + x2.z + x3.z);
    o4.w = oa[bb][3] + 0.25f * (x0.w + x1.w + x2.w + x3.w);
    *(float4*)(out + ((size_t)b * NN + n) * 256 + (lane << 2)) = o4;
  }
}

extern "C" void kernel_launch(void* const* d_in, const int* in_sizes, int n_in,
                              void* d_out, int out_size, void* d_ws, size_t ws_size,
                              hipStream_t stream) {
  const float* x   = (const float*)d_in[0];
  const float* ftl = (const float*)d_in[1];
  const float* ftr = (const float*)d_in[2];
  const float* fbl = (const float*)d_in[3];
  const float* fbr = (const float*)d_in[4];
  const float* fo  = (const float*)d_in[5];
  const float* gn  = (const float*)d_in[6];
  float* o = (float*)d_out;
  cpquad_kernel<<<dim3(NN), dim3(512), 0, stream>>>(x, ftl, ftr, fbl, fbr, fo, gn, o);
}

// Round 10
// 215.204 us; speedup vs baseline: 1.1677x; 1.1677x over previous
//
#include <hip/hip_runtime.h>
#include <math.h>

// CPQuadRankLayer: B=16, N=2048, IN=OUT=256, R=64, Q=4.
// out[b,n,o] = sum_r ( prod_q rmsnorm_r(x[b,n,q,:] @ Fq[n]^T) )[r] * gain[n] * Fo[n,r,o]
//              + mean_q x[b,n,q,o]
//
// R10: wave-private DMA pipeline. Diagnosis across R5-R9: ~25% VALU util in
// every structure; R5 bound by barrier lock-step, R9 by load latency vs
// unroll-2 ILP. Here each wave stages ONLY data it consumes (its 32 factor
// rows + its quadrant's x, dup'd per rh-pair -> L2 absorbs) into a private
// 2-slot LDS ring via global_load_lds, with a per-wave counted vmcnt: issue
// p+1's 3 DMA ops, vmcnt(3), ds_read, 128 FMA. ZERO barriers in the main
// loop; in-flight data costs no VGPRs. LDS 48KB stream + 16.25KB P = 64.25KB
// -> 2 WG/CU; (512,2) -> 128-reg cap, ~90 live.

#define WAITVM(NLIT) asm volatile("s_waitcnt vmcnt(" #NLIT ")" ::: "memory")

__device__ __forceinline__ void g2l16(const float* g, float* l) {
  __builtin_amdgcn_global_load_lds(
      (const __attribute__((address_space(1))) void*)g,
      (__attribute__((address_space(3))) void*)l, 16, 0, 0);
}

#define NN 2048

__global__ __launch_bounds__(512, 2) void cpquad_kernel(
    const float* __restrict__ x,
    const float* __restrict__ ftl, const float* __restrict__ ftr,
    const float* __restrict__ fbl, const float* __restrict__ fbr,
    const float* __restrict__ fout, const float* __restrict__ gain,
    float* __restrict__ out) {

  // LDS: stream 8 waves x 2 slots x 768 floats (fv 512 + x 256) = 48KB,
  //      s_ps 16KB, s_rr 256B -> 64.25KB total.
  alignas(16) __shared__ float s_st[8 * 2 * 768];
  __shared__ float s_ps[4096]; // [4 q][16 b][64 r]; plane0 overwritten by merged
  __shared__ float s_rr[64];   // [4 q][16 b] 1/rms

  const int t = threadIdx.x, lane = t & 63, wid = t >> 6;
  const int n = blockIdx.x;
  const float gn = gain[n];

  // decomposition: t = qq(2b) | rg(4b) | bh(1b) | iseg(2b); rg bit3 == wid&1
  const int iseg = t & 3;         // 4-float i-slot
  const int bh   = (t >> 2) & 1;  // b half
  const int rg   = (t >> 3) & 15; // rows rg + {0,16,32,48}
  const int qq   = t >> 7;        // quadrant ( = wid>>1 )
  const int rh   = wid & 1;       // r-half (rg bit3)
  const int rj   = rg & 7;

  const float* fq0 = (qq == 0) ? ftl : ((qq == 1) ? ftr : ((qq == 2) ? fbl : fbr));

  // ---- per-lane DMA source pointers (wave-private stream) ----
  // fv op A: lane l -> row_local rl=l>>2 (k=rl>>3 in {0,1}, rj=rl&7), chunk c=l&3
  // fv op B: same with k+=2. x op: rl = b (0..15), chunk c.
  const int rl = lane >> 2, c = lane & 3;
  const float* pA = fq0 + ((size_t)n * 64 + (rl >> 3) * 16 + rh * 8 + (rl & 7)) * 256 + c * 4;
  const float* pB = pA + 8192; // k += 2 -> +2*16*256 floats
  const float* pX = x + (((size_t)rl * NN + n) * 4 + qq) * 256 + c * 4;

  float* wbase = s_st + wid * 1536; // 2 slots x 768

  // LDS slot layout: [0..511] fv rows [k*8+rj][16f]; [512..767] x rows [b][16f]
  auto ISSUE = [&](int p) {
    float* d = wbase + (p & 1) * 768;
    g2l16(pA + p * 16, d);
    g2l16(pB + p * 16, d + 256);
    g2l16(pX + p * 16, d + 512);
  };

  ISSUE(0);

  float acc[4][8];
#pragma unroll
  for (int k = 0; k < 4; ++k)
#pragma unroll
    for (int b = 0; b < 8; ++b) acc[k][b] = 0.0f;

  // ---------- projection: 16 i-slices, per-wave pipeline, NO barriers -------
#pragma unroll 2
  for (int p = 0; p < 16; ++p) {
    if (p < 15) {
      ISSUE(p + 1);      // queue: [S(p) 3, S(p+1) 3]
      WAITVM(3);         // S(p) landed; S(p+1) stays in flight
    } else {
      WAITVM(0);         // last slice
    }
    const float* sb = wbase + (p & 1) * 768;
    float4 fv[4];
#pragma unroll
    for (int k = 0; k < 4; ++k)
      fv[k] = *(const float4*)(sb + (k * 8 + rj) * 16 + iseg * 4);
#pragma unroll
    for (int h2 = 0; h2 < 2; ++h2) {
      float4 xv[4];
#pragma unroll
      for (int bb = 0; bb < 4; ++bb)
        xv[bb] = *(const float4*)(sb + 512 + (bh * 8 + h2 * 4 + bb) * 16 + iseg * 4);
#pragma unroll
      for (int k = 0; k < 4; ++k)
#pragma unroll
        for (int bb = 0; bb < 4; ++bb) {
          acc[k][h2 * 4 + bb] = fmaf(fv[k].x, xv[bb].x, acc[k][h2 * 4 + bb]);
          acc[k][h2 * 4 + bb] = fmaf(fv[k].y, xv[bb].y, acc[k][h2 * 4 + bb]);
          acc[k][h2 * 4 + bb] = fmaf(fv[k].z, xv[bb].z, acc[k][h2 * 4 + bb]);
          acc[k][h2 * 4 + bb] = fmaf(fv[k].w, xv[bb].w, acc[k][h2 * 4 + bb]);
        }
    }
    // slot reuse is intra-wave only: p-1's ds_reads were consumed by its FMAs
    // (compiler-inserted lgkm waits) before p+1's DMA was issued. No fence.
  }

  // ---------- reduce over iseg, write P ----------
#pragma unroll
  for (int k = 0; k < 4; ++k)
#pragma unroll
    for (int b = 0; b < 8; ++b) {
      float v = acc[k][b];
      v += __shfl_xor(v, 1);
      v += __shfl_xor(v, 2);
      acc[k][b] = v;
    }
#pragma unroll
  for (int k = 0; k < 4; ++k) {
    if (iseg == k) { // static acc index (rule #20)
#pragma unroll
      for (int b = 0; b < 8; ++b)
        s_ps[qq * 1024 + (bh * 8 + b) * 64 + k * 16 + rg] = acc[k][b];
    }
  }
  __syncthreads();

  // ---------- RMS per (q,b) row ----------
#pragma unroll
  for (int j = 0; j < 8; ++j) {
    const int row = wid * 8 + j; // row = q*16 + b
    const float v = s_ps[row * 64 + lane];
    float ssum = v * v;
#pragma unroll
    for (int d = 1; d < 64; d <<= 1) ssum += __shfl_xor(ssum, d);
    if (lane == 0) s_rr[row] = 1.0f / sqrtf(ssum * (1.0f / 64.0f) + 1e-6f);
  }
  __syncthreads();

  // ---------- merged[b][r] -> s_ps plane 0 (element-owned, race-free) -------
#pragma unroll
  for (int e0 = 0; e0 < 2; ++e0) {
    const int e = t + e0 * 512;
    const int b = e >> 6, r = e & 63;
    float m = gn;
#pragma unroll
    for (int q = 0; q < 4; ++q) m *= s_ps[q * 1024 + b * 64 + r] * s_rr[q * 16 + b];
    s_ps[b * 64 + r] = m;
  }
  __syncthreads();

  // ---------- out GEMM: direct coalesced fo reads (L1 broadcast) ------------
  const float mv0 = s_ps[(wid * 2 + 0) * 64 + lane];
  const float mv1 = s_ps[(wid * 2 + 1) * 64 + lane];
  const float* fo_n = fout + (size_t)n * 16384 + (lane << 2);

  float oa[2][4] = {{0.f, 0.f, 0.f, 0.f}, {0.f, 0.f, 0.f, 0.f}};
#pragma unroll 8
  for (int rr = 0; rr < 64; ++rr) {
    const float4 f4 = *(const float4*)(fo_n + rr * 256);
    const float m0 = __uint_as_float(__builtin_amdgcn_readlane(__float_as_uint(mv0), rr));
    const float m1 = __uint_as_float(__builtin_amdgcn_readlane(__float_as_uint(mv1), rr));
    oa[0][0] = fmaf(m0, f4.x, oa[0][0]); oa[0][1] = fmaf(m0, f4.y, oa[0][1]);
    oa[0][2] = fmaf(m0, f4.z, oa[0][2]); oa[0][3] = fmaf(m0, f4.w, oa[0][3]);
    oa[1][0] = fmaf(m1, f4.x, oa[1][0]); oa[1][1] = fmaf(m1, f4.y, oa[1][1]);
    oa[1][2] = fmaf(m1, f4.z, oa[1][2]); oa[1][3] = fmaf(m1, f4.w, oa[1][3]);
  }

  // ---------- residual: tail re-read of x (coalesced, L2/L3-warm) + store ---
#pragma unroll
  for (int bb = 0; bb < 2; ++bb) {
    const int b = wid * 2 + bb;
    const float* xe = x + (((size_t)b * NN + n) * 4) * 256 + (lane << 2);
    float4 x0 = *(const float4*)(xe);
    float4 x1 = *(const float4*)(xe + 256);
    float4 x2 = *(const float4*)(xe + 512);
    float4 x3 = *(const float4*)(xe + 768);
    float4 o4;
    o4.x = oa[bb][0] + 0.25f * (x0.x + x1.x + x2.x + x3.x);
    o4.y = oa[bb][1] + 0.25f * (x0.y + x1.y + x2.y + x3.y);
    o4.z = oa[bb][2] + 0.25f * (x0.z + x1.z + x2.z + x3.z);
    o4.w = oa[bb][3] + 0.25f * (x0.w + x1.w + x2.w + x3.w);
    *(float4*)(out + ((size_t)b * NN + n) * 256 + (lane << 2)) = o4;
  }
}

extern "C" void kernel_launch(void* const* d_in, const int* in_sizes, int n_in,
                              void* d_out, int out_size, void* d_ws, size_t ws_size,
                              hipStream_t stream) {
  const float* x   = (const float*)d_in[0];
  const float* ftl = (const float*)d_in[1];
  const float* ftr = (const float*)d_in[2];
  const float* fbl = (const float*)d_in[3];
  const float* fbr = (const float*)d_in[4];
  const float* fo  = (const float*)d_in[5];
  const float* gn  = (const float*)d_in[6];
  float* o = (float*)d_out;
  cpquad_kernel<<<dim3(NN), dim3(512), 0, stream>>>(x, ftl, ftr, fbl, fbr, fo, gn, o);
}

// Round 13
// 212.892 us; speedup vs baseline: 1.1803x; 1.0109x over previous
//
#include <hip/hip_runtime.h>
#include <math.h>

// CPQuadRankLayer: B=16, N=2048, IN=OUT=256, R=64, Q=4.
// out[b,n,o] = sum_r ( prod_q rmsnorm_r(x[b,n,q,:] @ Fq[n]^T) )[r] * gain[n] * Fo[n,r,o]
//              + mean_q x[b,n,q,o]
//
// R13 = R12 (wave-private zero-barrier DMA pipeline, depth-2, 3-slot rings,
// s_ps aliased onto the stream) + THE RACE FIX: s_waitcnt lgkmcnt(0) at the
// end of each phase body. R11/R12 failed with DIFFERENT absmax (1.80/2.14)
// on identical inputs => timing race, not indexing (all ring/swizzle indices
// re-verified by lane simulation). Root cause per rule #18: the compiler may
// sink phase p-1's register-only FMAs (with their auto-lgkm waits) past the
// asm fences and past phase p's global_load_lds; a ds_read can then still be
// QUEUED (congested DS pipe) when the same-slot DMA lands from a warm L2
// (~250cy) -> stale data. lgkmcnt(0) is memory-ordered: ds_reads can't sink
// below it, the next DMA can't hoist above it -> reads COMPLETE before the
// overwriting DMA issues. Steady-state cost ~0 (reads done ~150cy into phase).

#define WAITVM(NLIT) asm volatile("s_waitcnt vmcnt(" #NLIT ")" ::: "memory")
#define LGKM0()      asm volatile("s_waitcnt lgkmcnt(0)" ::: "memory")
#define MEMFENCE()   asm volatile("" ::: "memory")

__device__ __forceinline__ void g2l16(const float* g, float* l) {
  __builtin_amdgcn_global_load_lds(
      (const __attribute__((address_space(1))) void*)g,
      (__attribute__((address_space(3))) void*)l, 16, 0, 0);
}

#define NN 2048

__global__ __launch_bounds__(512, 2) void cpquad_kernel(
    const float* __restrict__ x,
    const float* __restrict__ ftl, const float* __restrict__ ftr,
    const float* __restrict__ fbl, const float* __restrict__ fbr,
    const float* __restrict__ fout, const float* __restrict__ gain,
    float* __restrict__ out) {

  // Stream: per wave 3 fv slots (512 f) + 3 x slots (256 f) = 2304 floats.
  // 8 waves -> 18432 floats = 72KB. s_ps (4096 f) aliases the front after
  // sync #1 (per-wave vmcnt drained at p=15; reads data-dep complete).
  alignas(16) __shared__ float s_st[8 * 2304];
  float* s_ps = s_st; // [4 q][16 b][64 r]

  const int t = threadIdx.x, lane = t & 63, wid = t >> 6;
  const int n = blockIdx.x;
  const float gn = gain[n];

  // decomposition: t = qq(2b) | rg(4b) | bh(1b) | iseg(2b); rg bit3 == wid&1
  const int iseg = t & 3;         // 4-float i-slot
  const int bh   = (t >> 2) & 1;  // b half
  const int rg   = (t >> 3) & 15; // rows rg + {0,16,32,48}
  const int qq   = t >> 7;        // quadrant ( = wid>>1 )
  const int rh   = wid & 1;       // r-half (rg bit3)
  const int rj   = rg & 7;
  const int fsl  = (iseg ^ (rj & 3)) << 2; // swizzled fv slot (floats)

  const float* fq0 = (qq == 0) ? ftl : ((qq == 1) ? ftr : ((qq == 2) ? fbl : fbr));

  // ---- per-lane DMA sources (wave-private stream) ----
  // fv op A: lane l -> local row rl=l>>2 (khalf=rl>>3, rj=rl&7), chunk c=l&3.
  // Source chunk XOR-swizzled by local_row&3 (== rl&3); reader undoes via fsl.
  // fv op B: same rows +32 (k=2,3). x: row rl=b (0..15), chunk c, linear.
  const int rl = lane >> 2, c = lane & 3;
  const float* pA = fq0 + ((size_t)n * 64 + (rl >> 3) * 16 + rh * 8 + (rl & 7)) * 256
                        + ((c ^ (rl & 3)) << 2);
  const float* pB = pA + 8192; // +32 global rows
  const float* pX = x + (((size_t)rl * NN + n) * 4 + qq) * 256 + (c << 2);

  float* wf = s_st + wid * 2304;        // fv slots: 3 x 512 floats
  float* wx = wf + 1536;                // x slots: 3 x 256 floats

  auto ISSUE_F = [&](int s) {
    float* d = wf + (s % 3) * 512;
    g2l16(pA + s * 16, d);
    g2l16(pB + s * 16, d + 256);
  };
  auto ISSUE_X = [&](int s) {
    g2l16(pX + s * 16, wx + (s % 3) * 256);
  };

  // prologue: groups pinned contiguous in the vmem queue by fences
  ISSUE_F(0); ISSUE_X(0);
  MEMFENCE();
  ISSUE_F(1); ISSUE_X(1);
  MEMFENCE();

  float acc[4][8];
#pragma unroll
  for (int k = 0; k < 4; ++k)
#pragma unroll
    for (int b = 0; b < 8; ++b) acc[k][b] = 0.0f;

  // ---------- projection: 16 i-slices, per-wave depth-2 pipeline, NO barriers
#pragma unroll 2
  for (int p = 0; p < 16; ++p) {
    // steady queue entering p: [F(p)2, X(p)1, F(p+1)2, X(p+1)1] = 6
    if (p < 14) {
      ISSUE_F(p + 2);  // slot (p+2)%3: last read in phase p-1, reads COMPLETE
      ISSUE_X(p + 2);  //   (end-of-phase lgkmcnt(0) below) -> overwrite safe
      WAITVM(6);       // retire F(p)+X(p); (p+1),(p+2) groups stay in flight
    } else if (p == 14) {
      WAITVM(3);       // retire F14,X14; [F15,X15] in flight
    } else {
      WAITVM(0);       // last slice
    }
    const float* sb = wf + (p % 3) * 512;
    const float* xb = wx + (p % 3) * 256;
    float4 fv[4];
#pragma unroll
    for (int k = 0; k < 4; ++k)
      fv[k] = *(const float4*)(sb + (k * 8 + rj) * 16 + fsl);
#pragma unroll
    for (int h2 = 0; h2 < 2; ++h2) {
      float4 xv[4];
#pragma unroll
      for (int bb = 0; bb < 4; ++bb)
        xv[bb] = *(const float4*)(xb + (bh * 8 + h2 * 4 + bb) * 16 + iseg * 4);
#pragma unroll
      for (int k = 0; k < 4; ++k)
#pragma unroll
        for (int bb = 0; bb < 4; ++bb) {
          acc[k][h2 * 4 + bb] = fmaf(fv[k].x, xv[bb].x, acc[k][h2 * 4 + bb]);
          acc[k][h2 * 4 + bb] = fmaf(fv[k].y, xv[bb].y, acc[k][h2 * 4 + bb]);
          acc[k][h2 * 4 + bb] = fmaf(fv[k].z, xv[bb].z, acc[k][h2 * 4 + bb]);
          acc[k][h2 * 4 + bb] = fmaf(fv[k].w, xv[bb].w, acc[k][h2 * 4 + bb]);
        }
    }
    // RACE FIX: force this phase's ds_reads to COMPLETE (sample LDS) before
    // the next phase's same-slot DMA is issued. Memory-ordered both ways.
    LGKM0();
  }

  // ---------- reduce over iseg ----------
#pragma unroll
  for (int k = 0; k < 4; ++k)
#pragma unroll
    for (int b = 0; b < 8; ++b) {
      float v = acc[k][b];
      v += __shfl_xor(v, 1);
      v += __shfl_xor(v, 2);
      acc[k][b] = v;
    }
  __syncthreads(); // sync #1: stream dead everywhere -> s_ps may alias
#pragma unroll
  for (int k = 0; k < 4; ++k) {
    if (iseg == k) { // static acc index (rule #20)
#pragma unroll
      for (int b = 0; b < 8; ++b)
        s_ps[qq * 1024 + (bh * 8 + b) * 64 + k * 16 + rg] = acc[k][b];
    }
  }
  __syncthreads(); // sync #2: P visible

  // ---------- RMS per (q,b) row: scale row in place (rr on all lanes) -------
#pragma unroll
  for (int j = 0; j < 8; ++j) {
    const int row = wid * 8 + j; // row = q*16 + b
    float v = s_ps[row * 64 + lane];
    float ssum = v * v;
#pragma unroll
    for (int d = 1; d < 64; d <<= 1) ssum += __shfl_xor(ssum, d);
    v *= 1.0f / sqrtf(ssum * (1.0f / 64.0f) + 1e-6f);
    s_ps[row * 64 + lane] = v;
  }
  __syncthreads(); // sync #3: normalized P visible

  // ---------- merged[b][r] -> s_ps plane 0 (element-owned, race-free) -------
#pragma unroll
  for (int e0 = 0; e0 < 2; ++e0) {
    const int e = t + e0 * 512;
    const int b = e >> 6, r = e & 63;
    float m = gn;
#pragma unroll
    for (int q = 0; q < 4; ++q) m *= s_ps[q * 1024 + b * 64 + r];
    s_ps[b * 64 + r] = m;
  }
  __syncthreads(); // sync #4: merged visible

  // ---------- out GEMM: direct coalesced fo reads (L1/L2 broadcast) ---------
  const float mv0 = s_ps[(wid * 2 + 0) * 64 + lane];
  const float mv1 = s_ps[(wid * 2 + 1) * 64 + lane];
  const float* fo_n = fout + (size_t)n * 16384 + (lane << 2);

  float oa[2][4] = {{0.f, 0.f, 0.f, 0.f}, {0.f, 0.f, 0.f, 0.f}};
#pragma unroll 8
  for (int rr = 0; rr < 64; ++rr) {
    const float4 f4 = *(const float4*)(fo_n + rr * 256);
    const float m0 = __uint_as_float(__builtin_amdgcn_readlane(__float_as_uint(mv0), rr));
    const float m1 = __uint_as_float(__builtin_amdgcn_readlane(__float_as_uint(mv1), rr));
    oa[0][0] = fmaf(m0, f4.x, oa[0][0]); oa[0][1] = fmaf(m0, f4.y, oa[0][1]);
    oa[0][2] = fmaf(m0, f4.z, oa[0][2]); oa[0][3] = fmaf(m0, f4.w, oa[0][3]);
    oa[1][0] = fmaf(m1, f4.x, oa[1][0]); oa[1][1] = fmaf(m1, f4.y, oa[1][1]);
    oa[1][2] = fmaf(m1, f4.z, oa[1][2]); oa[1][3] = fmaf(m1, f4.w, oa[1][3]);
  }

  // ---------- residual: tail re-read of x (coalesced, L2/L3-warm) + store ---
#pragma unroll
  for (int bb = 0; bb < 2; ++bb) {
    const int b = wid * 2 + bb;
    const float* xe = x + (((size_t)b * NN + n) * 4) * 256 + (lane << 2);
    float4 x0 = *(const float4*)(xe);
    float4 x1 = *(const float4*)(xe + 256);
    float4 x2 = *(const float4*)(xe + 512);
    float4 x3 = *(const float4*)(xe + 768);
    float4 o4;
    o4.x = oa[bb][0] + 0.25f * (x0.x + x1.x + x2.x + x3.x);
    o4.y = oa[bb][1] + 0.25f * (x0.y + x1.y + x2.y + x3.y);
    o4.z = oa[bb][2] + 0.25f * (x0.z + x1.z + x2.z + x3.z);
    o4.w = oa[bb][3] + 0.25f * (x0.w + x1.w + x2.w + x3.w);
    *(float4*)(out + ((size_t)b * NN + n) * 256 + (lane << 2)) = o4;
  }
}

extern "C" void kernel_launch(void* const* d_in, const int* in_sizes, int n_in,
                              void* d_out, int out_size, void* d_ws, size_t ws_size,
                              hipStream_t stream) {
  const float* x   = (const float*)d_in[0];
  const float* ftl = (const float*)d_in[1];
  const float* ftr = (const float*)d_in[2];
  const float* fbl = (const float*)d_in[3];
  const float* fbr = (const float*)d_in[4];
  const float* fo  = (const float*)d_in[5];
  const float* gn  = (const float*)d_in[6];
  float* o = (float*)d_out;
  cpquad_kernel<<<dim3(NN), dim3(512), 0, stream>>>(x, ftl, ftr, fbl, fbr, fo, gn, o);
}